// Round 10
// baseline (493.527 us; speedup 1.0000x reference)
//
#include <hip/hip_runtime.h>
#include <hip/hip_bf16.h>

// 2-layer GCN + CORAL head. r9 champion + L2-resident sliced aggregation.
//  - edge compaction int64->int32 + fused degree histogram (1 pass)
//  - scan1(+deg_inv_sqrt) -> scan2 -> dst-partitioned counting-sort fill
//  - split-bf16 MFMA GEMM, 3 products; epilogue scales by deg_inv_sqrt[r],
//    stores bf16 SLICE-MAJOR: 8 slices x 16 cols, 3.2 MB/slice plane
//  - aggregation: slice = blockIdx&7 (round-robin -> one XCD per slice, plane
//    L2-resident; r7-proven FETCH drop). Wave = 8 nodes x 8 lanes/node:
//    full edge list per 8-lane group, no shuffles, unroll 8. (r7's failure
//    was 1 node/wave -> fixed cost dominated; this amortizes it 8x.)
//  - layer-1 agg fuses relu + bf16 hi/lo (slice planes); layer-2 agg emits
//    per-slice CORAL partials; reduce_head adds th_bias. 11 dispatches.

#define FEAT 128
#define CHUNK 4096
typedef unsigned short u16;
typedef unsigned int u32;
typedef __attribute__((ext_vector_type(8))) short bf16x8;
typedef __attribute__((ext_vector_type(4))) float f32x4;
#define MFMA16 __builtin_amdgcn_mfma_f32_16x16x32_bf16

__device__ inline u16 f2bf(float f) {
    __hip_bfloat16 b = __float2bfloat16(f);
    return __builtin_bit_cast(u16, b);
}
__device__ inline float bf2f(u16 u) {
    __hip_bfloat16 b = __builtin_bit_cast(__hip_bfloat16, u);
    return __bfloat162float(b);
}
__device__ inline float blo(u32 m) { return __uint_as_float(m << 16); }
__device__ inline float bhi(u32 m) { return __uint_as_float(m & 0xffff0000u); }

// ------------- compact edges to int32 + degree histogram (detect inlined) ----
__global__ __launch_bounds__(256) void compact_count(const int* __restrict__ p,
                                                     int* __restrict__ src32,
                                                     int* __restrict__ dst32,
                                                     int* __restrict__ cnt, int E) {
    __shared__ int sflag;
    if (threadIdx.x < 64) {
        int v = p[2 * (int)threadIdx.x + 1];
        unsigned long long b = __ballot(v != 0);
        if (threadIdx.x == 0) sflag = (b == 0ull) ? 1 : 0;
    }
    __syncthreads();
    const int m = sflag;
    int i = blockIdx.x * 256 + threadIdx.x;
    if (i >= E) return;
    int s, d;
    if (m) { s = p[2 * (size_t)i]; d = p[2 * ((size_t)E + i)]; }
    else   { s = p[(size_t)i];     d = p[(size_t)E + i]; }
    src32[i] = s;
    dst32[i] = d;
    atomicAdd(&cnt[d], 1);
}

// ---------------- scan1: block-exclusive scan + fused deg_inv_sqrt ----------
__global__ void scan1(const int* __restrict__ cnt, int* __restrict__ out,
                      int* __restrict__ bsum, float* __restrict__ dis, int n) {
    __shared__ int tmp[256];
    int base = blockIdx.x * 2048;
    int idx = base + threadIdx.x * 8;
    int v[8]; int s = 0;
#pragma unroll
    for (int i = 0; i < 8; ++i) {
        int id = idx + i;
        v[i] = (id < n) ? cnt[id] : 0;
        s += v[i];
        if (id < n) dis[id] = 1.0f / sqrtf((float)v[i] + 1.0f);
    }
    tmp[threadIdx.x] = s;
    __syncthreads();
    for (int off = 1; off < 256; off <<= 1) {
        int t = (threadIdx.x >= (unsigned)off) ? tmp[threadIdx.x - off] : 0;
        __syncthreads();
        tmp[threadIdx.x] += t;
        __syncthreads();
    }
    int excl = (threadIdx.x == 0) ? 0 : tmp[threadIdx.x - 1];
    if (threadIdx.x == 255) bsum[blockIdx.x] = tmp[255];
    int run = excl;
#pragma unroll
    for (int i = 0; i < 8; ++i) { int id = idx + i; if (id < n) out[id] = run; run += v[i]; }
}

__global__ void scan2(int* __restrict__ bsum, int nb) {
    __shared__ int tmp[256];
    int v = (threadIdx.x < (unsigned)nb) ? bsum[threadIdx.x] : 0;
    tmp[threadIdx.x] = v;
    __syncthreads();
    for (int off = 1; off < 256; off <<= 1) {
        int t = (threadIdx.x >= (unsigned)off) ? tmp[threadIdx.x - off] : 0;
        __syncthreads();
        tmp[threadIdx.x] += t;
        __syncthreads();
    }
    int excl = (threadIdx.x == 0) ? 0 : tmp[threadIdx.x - 1];
    if (threadIdx.x < (unsigned)nb) bsum[threadIdx.x] = excl;
}

// ---------------- counting-sort fill, dst-partitioned (8 XCD slices) ---------
// pos = bsum[d>>11] + fetch_add(rowp[d]). After this kernel:
//   beg(d) = bsum[d>>11] + rowp[d] - cnt[d]
__global__ __launch_bounds__(256) void fill_sorted(const int* __restrict__ src32,
                                                   const int* __restrict__ dst32,
                                                   int* __restrict__ rowp,
                                                   const int* __restrict__ bsum,
                                                   int* __restrict__ ssrc, int E,
                                                   int nper) {
    const int part = blockIdx.x & 7;
    const int lo = part * nper, hi = lo + nper;
    const int i0 = (int)(blockIdx.x >> 3) * CHUNK;
    const int iend = min(i0 + CHUNK, E);
    for (int i = i0 + threadIdx.x; i < iend; i += 256) {
        int d = dst32[i];
        if (d >= lo && d < hi) {
            int pos = bsum[d >> 11] + atomicAdd(&rowp[d], 1);
            ssrc[pos] = src32[i];
        }
    }
}

// ---- W1,W2 [k][col] fp32 -> transposed bf16 hi/lo planes [2][col][k] -------
__global__ void conv_w(const float* __restrict__ W1, const float* __restrict__ W2,
                       u16* __restrict__ th, u16* __restrict__ tl) {
    const int b = blockIdx.x;                  // 128 blocks
    const float* W = (b < 64) ? W1 : W2;
    const int base = (b < 64) ? 0 : 16384;
    int idx = (b & 63) * 256 + threadIdx.x;    // 16384 per matrix
    int k = idx >> 7, col = idx & 127;
    float v = W[idx];
    u16 h = f2bf(v);
    u16 l = f2bf(v - bf2f(h));
    th[base + col * 128 + k] = h;
    tl[base + col * 128 + k] = l;
}

// -------- MFMA GEMM -> slice-major bf16: G[s][r][c16], s=col/16 -------------
// 3-product split: ah*bh + al*bh + ah*bl  (al*bl ~ 2^-18, dropped).
// FP32IN: X fp32, hi/lo split in-register. Else X bf16 hi/lo slice planes.
template <bool FP32IN>
__global__ __launch_bounds__(256) void gemm_mfma(
    const float* __restrict__ Xf,
    const u16* __restrict__ Xhi, const u16* __restrict__ Xlo,
    const u16* __restrict__ Whi, const u16* __restrict__ Wlo,
    const float* __restrict__ dis, u16* __restrict__ G, int n, int nt) {
    const int wave = threadIdx.x >> 6, lane = threadIdx.x & 63;
    const int l15 = lane & 15, hi4 = lane >> 4;

    bf16x8 bh[2][4], bl[2][4];
#pragma unroll
    for (int ct = 0; ct < 2; ++ct) {
        const int col = wave * 32 + ct * 16 + l15;
#pragma unroll
        for (int j = 0; j < 4; ++j) {
            const int off = col * 128 + j * 32 + hi4 * 8;
            bh[ct][j] = *(const bf16x8*)(Whi + off);
            bl[ct][j] = *(const bf16x8*)(Wlo + off);
        }
    }

    for (int rt = blockIdx.x; rt < nt; rt += gridDim.x) {
        const int r0 = rt * 16;
        const int row = min(r0 + l15, n - 1);
        bf16x8 ah[4], al[4];
        if (FP32IN) {
            const float* Xr = Xf + (size_t)row * FEAT;
#pragma unroll
            for (int j = 0; j < 4; ++j) {
                float4 v0 = *(const float4*)(Xr + j * 32 + hi4 * 8);
                float4 v1 = *(const float4*)(Xr + j * 32 + hi4 * 8 + 4);
                float vv[8] = {v0.x, v0.y, v0.z, v0.w, v1.x, v1.y, v1.z, v1.w};
                bf16x8 h8, l8;
#pragma unroll
                for (int e = 0; e < 8; ++e) {
                    u16 h = f2bf(vv[e]);
                    u16 l = f2bf(vv[e] - bf2f(h));
                    h8[e] = (short)h; l8[e] = (short)l;
                }
                ah[j] = h8; al[j] = l8;
            }
        } else {
            // cols j*32+hi4*8..+7: slice sl = j*2+(hi4>>1), offset (hi4&1)*8
#pragma unroll
            for (int j = 0; j < 4; ++j) {
                const int sl = j * 2 + (hi4 >> 1);
                const size_t off = ((size_t)sl * n + row) * 16 + (hi4 & 1) * 8;
                ah[j] = *(const bf16x8*)(Xhi + off);
                al[j] = *(const bf16x8*)(Xlo + off);
            }
        }
        float dr[4];
#pragma unroll
        for (int q = 0; q < 4; ++q) {
            const int r = r0 + hi4 * 4 + q;
            dr[q] = (r < n) ? dis[r] : 0.f;
        }
#pragma unroll
        for (int ct = 0; ct < 2; ++ct) {
            f32x4 a = {0.f, 0.f, 0.f, 0.f};
#pragma unroll
            for (int j = 0; j < 4; ++j) {
                a = MFMA16(ah[j], bh[ct][j], a, 0, 0, 0);
                a = MFMA16(al[j], bh[ct][j], a, 0, 0, 0);
                a = MFMA16(ah[j], bl[ct][j], a, 0, 0, 0);
            }
            const int s = wave * 2 + ct;      // slice
#pragma unroll
            for (int q = 0; q < 4; ++q) {
                const int r = r0 + hi4 * 4 + q;
                if (r < n)
                    G[((size_t)s * n + r) * 16 + l15] = f2bf(a[q] * dr[q]);
            }
        }
    }
}

// ---------------- L2-resident sliced pull aggregate ----------------
// slice = blockIdx&7 (one XCD per slice; 3.2MB plane L2-resident).
// Wave = 8 nodes x 8 lanes: lane = slot*8 + c; group runs its node's full
// edge list (divergent loop, unroll 8); lane owns cols 2c,2c+1 of its node.
// MODE 0: relu(dn*sum+b) -> bf16 hi/lo slice planes
// MODE 1: per-slice CORAL partial -> part[slice][node]
template <int MODE>
__global__ __launch_bounds__(256) void agg_sliced(
    const u16* __restrict__ G, const int* __restrict__ rowp,
    const int* __restrict__ cnt, const int* __restrict__ bsum,
    const int* __restrict__ ssrc, const float* __restrict__ dis,
    const float* __restrict__ bias,
    u16* __restrict__ Ohi, u16* __restrict__ Olo,
    float* __restrict__ part, const float* __restrict__ wfc, int n) {
    const int slice = blockIdx.x & 7;
    const int wave = threadIdx.x >> 6, lane = threadIdx.x & 63;
    const int c = lane & 7;                 // col-pair within slice
    const int slot = lane >> 3;             // node slot 0..7
    const int node = (int)(blockIdx.x >> 3) * 32 + wave * 8 + slot;
    const u32* __restrict__ Gs = (const u32*)G + (size_t)slice * n * 8;
    if (node >= n) return;
    const int deg = cnt[node];
    const int beg = bsum[node >> 11] + rowp[node] - deg;
    u32 mself = Gs[(size_t)node * 8 + c];
    float ax = blo(mself), ay = bhi(mself);
    int k = 0;
    for (; k + 8 <= deg; k += 8) {
        int s[8];
#pragma unroll
        for (int u = 0; u < 8; ++u) s[u] = ssrc[beg + k + u];
        u32 m[8];
#pragma unroll
        for (int u = 0; u < 8; ++u) m[u] = Gs[(size_t)s[u] * 8 + c];
#pragma unroll
        for (int u = 0; u < 8; ++u) { ax += blo(m[u]); ay += bhi(m[u]); }
    }
    for (; k < deg; ++k) {
        u32 m = Gs[(size_t)ssrc[beg + k] * 8 + c];
        ax += blo(m); ay += bhi(m);
    }
    const float dn = dis[node];
    const float2 bv = ((const float2*)bias)[slice * 8 + c];
    const float o0 = fmaxf(fmaf(dn, ax, bv.x), 0.f);
    const float o1 = fmaxf(fmaf(dn, ay, bv.y), 0.f);
    if (MODE == 0) {
        u16 h0 = f2bf(o0), h1 = f2bf(o1);
        u32 hp = (u32)h0 | ((u32)h1 << 16);
        u32 lp = (u32)f2bf(o0 - bf2f(h0)) | ((u32)f2bf(o1 - bf2f(h1)) << 16);
        ((u32*)Ohi)[((size_t)slice * n + node) * 8 + c] = hp;
        ((u32*)Olo)[((size_t)slice * n + node) * 8 + c] = lp;
    } else {
        const float2 wv = ((const float2*)wfc)[slice * 8 + c];
        float p = fmaf(o0, wv.x, o1 * wv.y);
        p += __shfl_xor(p, 1, 64);
        p += __shfl_xor(p, 2, 64);
        p += __shfl_xor(p, 4, 64);
        if (c == 0) part[(size_t)slice * n + node] = p;
    }
}

// ---------------- head reduce: out[i][k] = thb[k] + sum_s part[s][i] --------
__global__ void reduce_head(const float* __restrict__ part,
                            const float* __restrict__ thb,
                            float* __restrict__ out, int n) {
    int i = blockIdx.x * 256 + threadIdx.x;
    if (i >= n) return;
    float t = 0.f;
#pragma unroll
    for (int s = 0; s < 8; ++s) t += part[(size_t)s * n + i];
    float4 o = {t + thb[0], t + thb[1], t + thb[2], t + thb[3]};
    ((float4*)out)[i] = o;
}

extern "C" void kernel_launch(void* const* d_in, const int* in_sizes, int n_in,
                              void* d_out, int out_size, void* d_ws, size_t ws_size,
                              hipStream_t stream) {
    const float* x   = (const float*)d_in[0];
    const int*   ei  = (const int*)d_in[1];
    const float* W1  = (const float*)d_in[2];
    const float* b1  = (const float*)d_in[3];
    const float* W2  = (const float*)d_in[4];
    const float* b2  = (const float*)d_in[5];
    const float* wfc = (const float*)d_in[6];
    const float* thb = (const float*)d_in[7];
    const int N = in_sizes[0] / FEAT;
    const int E = in_sizes[1] / 2;
    float* out = (float*)d_out;

    char* w = (char*)d_ws;
    int*   bsum  = (int*)w;                       // [<=256]
    int*   deg   = (int*)(w + 1024);              // [N]  (= cnt)
    int*   rowp  = deg + N;                       // [N]
    float* dis   = (float*)(rowp + N);            // [N]
    int*   src32 = (int*)(dis + N);               // [E]
    int*   dst32 = src32 + E;                     // [E]
    int*   ssrc  = dst32 + E;                     // [E]
    size_t off   = (((char*)(ssrc + E)) - w + 511) & ~(size_t)511;
    u16*   wh    = (u16*)(w + off);               // [2][128*128] hi (W1,W2)
    u16*   wl    = wh + 32768;                    // [2][128*128] lo
    u16*   g     = wl + 32768;                    // [8][N][16] slice planes
    u16*   h1h   = g + (size_t)N * FEAT;          // [8][N][16]
    u16*   h1l   = h1h + (size_t)N * FEAT;        // [8][N][16]
    float* part  = (float*)(h1l + (size_t)N * FEAT);  // [8][N]

    const int nper = (N + 7) / 8;
    const int nch  = (E + CHUNK - 1) / CHUNK;
    const int NB   = (N + 2047) / 2048;

    hipMemsetAsync(deg, 0, (size_t)N * 4, stream);
    compact_count<<<(E + 255) / 256, 256, 0, stream>>>(ei, src32, dst32, deg, E);
    scan1<<<NB, 256, 0, stream>>>(deg, rowp, bsum, dis, N);
    scan2<<<1, 256, 0, stream>>>(bsum, NB);
    fill_sorted<<<nch * 8, 256, 0, stream>>>(src32, dst32, rowp, bsum, ssrc, E, nper);

    conv_w<<<128, 256, 0, stream>>>(W1, W2, wh, wl);

    const int nt = (N + 15) / 16;
    const int gblocks = nt < 1024 ? nt : 1024;
    const int ablocks = 8 * ((N + 31) / 32);
    gemm_mfma<true><<<gblocks, 256, 0, stream>>>(x, nullptr, nullptr, wh, wl,
                                                 dis, g, N, nt);
    agg_sliced<0><<<ablocks, 256, 0, stream>>>(g, rowp, deg, bsum, ssrc, dis, b1,
                                               h1h, h1l, nullptr, nullptr, N);
    gemm_mfma<false><<<gblocks, 256, 0, stream>>>(nullptr, h1h, h1l, wh + 16384,
                                                  wl + 16384, dis, g, N, nt);
    agg_sliced<1><<<ablocks, 256, 0, stream>>>(g, rowp, deg, bsum, ssrc, dis, b2,
                                               nullptr, nullptr, part, wfc, N);
    reduce_head<<<(N + 255) / 256, 256, 0, stream>>>(part, thb, out, N);
}

// Round 11
// 451.689 us; speedup vs baseline: 1.0926x; 1.0926x over previous
//
#include <hip/hip_runtime.h>
#include <hip/hip_bf16.h>

// 2-layer GCN + CORAL head. r9 champion + gemm2-into-agg1 fusion.
//  - compact int64->int32 + degree histogram (vectorized, 2 edges/thread)
//  - scan1(+deg_inv_sqrt) -> scan2 -> dst-partitioned counting-sort fill
//  - gemm1: fp32 x staged+converted through LDS once per 16-row tile (kills
//    the 4x redundant load+convert of r9), 3-product split-bf16 MFMA,
//    epilogue scales by deg_inv_sqrt -> bf16 plane g
//  - agg_gemm (fused): r9 pull-aggregate (wave=node, 256B row gathers,
//    unroll 16) -> relu+bias -> hi/lo bf16 into LDS 16-row tile -> W2 MFMA
//    -> scaled bf16 plane g2.  Saves h1 50MB write + 51MB read + 1 dispatch.
//  - agg<1>: r9 aggregate over g2 + fused CORAL head. 9 dispatches.
// r7/r10 lesson: feature-sliced L2-resident agg cuts FETCH 3x but loses on
// 8x instruction overhead -> full-row gather (~2.5TB/s fabric) is the floor.

#define FEAT 128
#define CHUNK 4096
typedef unsigned short u16;
typedef unsigned int u32;
typedef __attribute__((ext_vector_type(8))) short bf16x8;
typedef __attribute__((ext_vector_type(4))) float f32x4;
#define MFMA16 __builtin_amdgcn_mfma_f32_16x16x32_bf16
#define LROW 68   // LDS row stride in u32 (272B: 16B-aligned, 2-way bank alias)

__device__ inline u16 f2bf(float f) {
    __hip_bfloat16 b = __float2bfloat16(f);
    return __builtin_bit_cast(u16, b);
}
__device__ inline float bf2f(u16 u) {
    __hip_bfloat16 b = __builtin_bit_cast(__hip_bfloat16, u);
    return __bfloat162float(b);
}
__device__ inline float blo(u32 m) { return __uint_as_float(m << 16); }
__device__ inline float bhi(u32 m) { return __uint_as_float(m & 0xffff0000u); }

// ------------- compact edges to int32 + degree histogram --------------------
__global__ __launch_bounds__(256) void compact_count(const int* __restrict__ p,
                                                     int* __restrict__ src32,
                                                     int* __restrict__ dst32,
                                                     int* __restrict__ cnt, int E) {
    __shared__ int sflag;
    if (threadIdx.x < 64) {
        int v = p[2 * (int)threadIdx.x + 1];
        unsigned long long b = __ballot(v != 0);
        if (threadIdx.x == 0) sflag = (b == 0ull) ? 1 : 0;
    }
    __syncthreads();
    const int m = sflag;
    const int i0 = (blockIdx.x * 256 + threadIdx.x) * 2;
    if (i0 >= E) return;
    const bool two = (i0 + 1 < E);
    const bool vec = two && ((E & 1) == 0);
    int s0, s1 = 0, d0, d1 = 0;
    if (vec && m) {
        int4 v = *(const int4*)(p + 2 * (size_t)i0);
        int4 w2 = *(const int4*)(p + 2 * ((size_t)E + (size_t)i0));
        s0 = v.x; s1 = v.z; d0 = w2.x; d1 = w2.z;
    } else if (vec) {
        int2 v = *(const int2*)(p + i0);
        int2 w2 = *(const int2*)(p + (size_t)E + i0);
        s0 = v.x; s1 = v.y; d0 = w2.x; d1 = w2.y;
    } else {
        if (m) { s0 = p[2 * (size_t)i0]; d0 = p[2 * ((size_t)E + i0)]; }
        else   { s0 = p[(size_t)i0];     d0 = p[(size_t)E + i0]; }
        if (two) {
            if (m) { s1 = p[2 * (size_t)(i0 + 1)]; d1 = p[2 * ((size_t)E + i0 + 1)]; }
            else   { s1 = p[(size_t)i0 + 1];       d1 = p[(size_t)E + i0 + 1]; }
        }
    }
    if (two) {
        *(int2*)(src32 + i0) = make_int2(s0, s1);
        *(int2*)(dst32 + i0) = make_int2(d0, d1);
        atomicAdd(&cnt[d0], 1);
        atomicAdd(&cnt[d1], 1);
    } else {
        src32[i0] = s0; dst32[i0] = d0;
        atomicAdd(&cnt[d0], 1);
    }
}

// ---------------- scan1: block-exclusive scan + fused deg_inv_sqrt ----------
__global__ void scan1(const int* __restrict__ cnt, int* __restrict__ out,
                      int* __restrict__ bsum, float* __restrict__ dis, int n) {
    __shared__ int tmp[256];
    int base = blockIdx.x * 2048;
    int idx = base + threadIdx.x * 8;
    int v[8]; int s = 0;
#pragma unroll
    for (int i = 0; i < 8; ++i) {
        int id = idx + i;
        v[i] = (id < n) ? cnt[id] : 0;
        s += v[i];
        if (id < n) dis[id] = 1.0f / sqrtf((float)v[i] + 1.0f);
    }
    tmp[threadIdx.x] = s;
    __syncthreads();
    for (int off = 1; off < 256; off <<= 1) {
        int t = (threadIdx.x >= (unsigned)off) ? tmp[threadIdx.x - off] : 0;
        __syncthreads();
        tmp[threadIdx.x] += t;
        __syncthreads();
    }
    int excl = (threadIdx.x == 0) ? 0 : tmp[threadIdx.x - 1];
    if (threadIdx.x == 255) bsum[blockIdx.x] = tmp[255];
    int run = excl;
#pragma unroll
    for (int i = 0; i < 8; ++i) { int id = idx + i; if (id < n) out[id] = run; run += v[i]; }
}

__global__ void scan2(int* __restrict__ bsum, int nb) {
    __shared__ int tmp[256];
    int v = (threadIdx.x < (unsigned)nb) ? bsum[threadIdx.x] : 0;
    tmp[threadIdx.x] = v;
    __syncthreads();
    for (int off = 1; off < 256; off <<= 1) {
        int t = (threadIdx.x >= (unsigned)off) ? tmp[threadIdx.x - off] : 0;
        __syncthreads();
        tmp[threadIdx.x] += t;
        __syncthreads();
    }
    int excl = (threadIdx.x == 0) ? 0 : tmp[threadIdx.x - 1];
    if (threadIdx.x < (unsigned)nb) bsum[threadIdx.x] = excl;
}

// ---------------- counting-sort fill, dst-partitioned (8 XCD slices) ---------
__global__ __launch_bounds__(256) void fill_sorted(const int* __restrict__ src32,
                                                   const int* __restrict__ dst32,
                                                   int* __restrict__ rowp,
                                                   const int* __restrict__ bsum,
                                                   int* __restrict__ ssrc, int E,
                                                   int nper) {
    const int part = blockIdx.x & 7;
    const int lo = part * nper, hi = lo + nper;
    const int i0 = (int)(blockIdx.x >> 3) * CHUNK;
    const int iend = min(i0 + CHUNK, E);
    for (int i = i0 + threadIdx.x; i < iend; i += 256) {
        int d = dst32[i];
        if (d >= lo && d < hi) {
            int pos = bsum[d >> 11] + atomicAdd(&rowp[d], 1);
            ssrc[pos] = src32[i];
        }
    }
}

// ---- W1,W2 [k][col] fp32 -> transposed bf16 hi/lo planes [2][col][k] -------
__global__ void conv_w(const float* __restrict__ W1, const float* __restrict__ W2,
                       u16* __restrict__ th, u16* __restrict__ tl) {
    const int b = blockIdx.x;                  // 128 blocks
    const float* W = (b < 64) ? W1 : W2;
    const int base = (b < 64) ? 0 : 16384;
    int idx = (b & 63) * 256 + threadIdx.x;    // 16384 per matrix
    int k = idx >> 7, col = idx & 127;
    float v = W[idx];
    u16 h = f2bf(v);
    u16 l = f2bf(v - bf2f(h));
    th[base + col * 128 + k] = h;
    tl[base + col * 128 + k] = l;
}

// -------- gemm1: G[r][c] = bf16( dis[r] * sum_k X[r][k] W1[k][c] ) ----------
// fp32 X staged+converted through LDS ONCE per 16-row tile (all 4 waves share).
// 3-product split: ah*bh + al*bh + ah*bl.
__global__ __launch_bounds__(256) void gemm1(
    const float* __restrict__ Xf,
    const u16* __restrict__ Whi, const u16* __restrict__ Wlo,
    const float* __restrict__ dis, u16* __restrict__ G, int n, int nt) {
    __shared__ u32 lhi[16 * LROW], llo[16 * LROW];
    const int wave = threadIdx.x >> 6, lane = threadIdx.x & 63;
    const int l15 = lane & 15, hi4 = lane >> 4;

    bf16x8 bh[2][4], bl[2][4];
#pragma unroll
    for (int ct = 0; ct < 2; ++ct) {
        const int col = wave * 32 + ct * 16 + l15;
#pragma unroll
        for (int j = 0; j < 4; ++j) {
            const int off = col * 128 + j * 32 + hi4 * 8;
            bh[ct][j] = *(const bf16x8*)(Whi + off);
            bl[ct][j] = *(const bf16x8*)(Wlo + off);
        }
    }

    for (int rt = blockIdx.x; rt < nt; rt += gridDim.x) {
        const int r0 = rt * 16;
        {   // cooperative stage+convert: thread t -> row t>>4, cols (t&15)*8..+7
            const int row = threadIdx.x >> 4;
            const int c8 = (threadIdx.x & 15) * 8;
            const int r = min(r0 + row, n - 1);
            const float* Xr = Xf + (size_t)r * FEAT + c8;
            float4 v0 = *(const float4*)Xr;
            float4 v1 = *(const float4*)(Xr + 4);
            float vv[8] = {v0.x, v0.y, v0.z, v0.w, v1.x, v1.y, v1.z, v1.w};
            u32 hp[4], lp[4];
#pragma unroll
            for (int e = 0; e < 4; ++e) {
                u16 h0 = f2bf(vv[2 * e]), h1 = f2bf(vv[2 * e + 1]);
                u16 l0 = f2bf(vv[2 * e] - bf2f(h0));
                u16 l1 = f2bf(vv[2 * e + 1] - bf2f(h1));
                hp[e] = (u32)h0 | ((u32)h1 << 16);
                lp[e] = (u32)l0 | ((u32)l1 << 16);
            }
            u32* dh = lhi + row * LROW + (c8 >> 1);
            u32* dl = llo + row * LROW + (c8 >> 1);
#pragma unroll
            for (int e = 0; e < 4; ++e) { dh[e] = hp[e]; dl[e] = lp[e]; }
        }
        __syncthreads();
        bf16x8 ah[4], al[4];
#pragma unroll
        for (int j = 0; j < 4; ++j) {
            const int idx = l15 * LROW + j * 16 + hi4 * 4;
            ah[j] = *(const bf16x8*)(lhi + idx);
            al[j] = *(const bf16x8*)(llo + idx);
        }
        float dr[4];
#pragma unroll
        for (int q = 0; q < 4; ++q) {
            const int r = r0 + hi4 * 4 + q;
            dr[q] = (r < n) ? dis[r] : 0.f;
        }
#pragma unroll
        for (int ct = 0; ct < 2; ++ct) {
            f32x4 a = {0.f, 0.f, 0.f, 0.f};
#pragma unroll
            for (int j = 0; j < 4; ++j) {
                a = MFMA16(ah[j], bh[ct][j], a, 0, 0, 0);
                a = MFMA16(al[j], bh[ct][j], a, 0, 0, 0);
                a = MFMA16(ah[j], bl[ct][j], a, 0, 0, 0);
            }
            const int c0 = wave * 32 + ct * 16 + l15;
#pragma unroll
            for (int q = 0; q < 4; ++q) {
                const int r = r0 + hi4 * 4 + q;
                if (r < n) G[(size_t)r * FEAT + c0] = f2bf(a[q] * dr[q]);
            }
        }
        __syncthreads();   // protect LDS before next tile's staging
    }
}

// -------- fused agg1 + W2 GEMM ----------------------------------------------
// Block = 16 nodes. Phase A: wave w aggregates nodes r0+w*4..+3 (r9 gather:
// wave=node, 64 lanes x u32, unroll 16), relu+bias, hi/lo bf16 -> LDS tile.
// Phase B: W2 MFMA on the tile (wave w = col-tiles 2w,2w+1; B-frags from
// L2-hot W2 planes), epilogue scales by dis -> bf16 plane g2.
__global__ __launch_bounds__(256) void agg_gemm(
    const u16* __restrict__ G, const int* __restrict__ rowp,
    const int* __restrict__ cnt, const int* __restrict__ bsum,
    const int* __restrict__ ssrc, const float* __restrict__ dis,
    const float* __restrict__ bias,
    const u16* __restrict__ W2hi, const u16* __restrict__ W2lo,
    u16* __restrict__ G2, int n) {
    __shared__ u32 lhi[16 * LROW], llo[16 * LROW];
    const int wave = threadIdx.x >> 6, lane = threadIdx.x & 63;
    const int l15 = lane & 15, hi4 = lane >> 4;
    const u32* __restrict__ Gv = (const u32*)G;
    const int r0 = blockIdx.x * 16;

    // ---- phase A: aggregate 4 nodes per wave ----
#pragma unroll 1
    for (int q = 0; q < 4; ++q) {
        const int row = wave * 4 + q;
        const int node = r0 + row;
        u32 hp = 0, lp = 0;
        if (node < n) {
            const int c = cnt[node];
            const int beg = bsum[node >> 11] + rowp[node] - c;
            const int end = beg + c;
            u32 uself = Gv[(size_t)node * 64 + lane];
            float ax = blo(uself), ay = bhi(uself);
            int j = beg;
            for (; j + 16 <= end; j += 16) {
                int s[16];
#pragma unroll
                for (int u = 0; u < 16; ++u) s[u] = ssrc[j + u];
                u32 m[16];
#pragma unroll
                for (int u = 0; u < 16; ++u) m[u] = Gv[(size_t)s[u] * 64 + lane];
#pragma unroll
                for (int u = 0; u < 16; ++u) { ax += blo(m[u]); ay += bhi(m[u]); }
            }
            for (; j + 4 <= end; j += 4) {
                int s[4];
#pragma unroll
                for (int u = 0; u < 4; ++u) s[u] = ssrc[j + u];
                u32 m[4];
#pragma unroll
                for (int u = 0; u < 4; ++u) m[u] = Gv[(size_t)s[u] * 64 + lane];
#pragma unroll
                for (int u = 0; u < 4; ++u) { ax += blo(m[u]); ay += bhi(m[u]); }
            }
            for (; j < end; ++j) {
                u32 m = Gv[(size_t)ssrc[j] * 64 + lane];
                ax += blo(m); ay += bhi(m);
            }
            const float dn = dis[node];
            const float2 bv = ((const float2*)bias)[lane];
            const float o0 = fmaxf(fmaf(dn, ax, bv.x), 0.f);
            const float o1 = fmaxf(fmaf(dn, ay, bv.y), 0.f);
            u16 h0 = f2bf(o0), h1 = f2bf(o1);
            u16 l0 = f2bf(o0 - bf2f(h0)), l1 = f2bf(o1 - bf2f(h1));
            hp = (u32)h0 | ((u32)h1 << 16);
            lp = (u32)l0 | ((u32)l1 << 16);
        }
        lhi[row * LROW + lane] = hp;
        llo[row * LROW + lane] = lp;
    }
    __syncthreads();

    // ---- phase B: W2 GEMM on the 16-row tile ----
    bf16x8 ah[4], al[4];
#pragma unroll
    for (int j = 0; j < 4; ++j) {
        const int idx = l15 * LROW + j * 16 + hi4 * 4;
        ah[j] = *(const bf16x8*)(lhi + idx);
        al[j] = *(const bf16x8*)(llo + idx);
    }
    float dr[4];
#pragma unroll
    for (int q = 0; q < 4; ++q) {
        const int r = r0 + hi4 * 4 + q;
        dr[q] = (r < n) ? dis[r] : 0.f;
    }
#pragma unroll
    for (int ct = 0; ct < 2; ++ct) {
        const int col = (wave * 2 + ct) * 16 + l15;
        bf16x8 bh[4], bl[4];
#pragma unroll
        for (int j = 0; j < 4; ++j) {
            const int off = col * 128 + j * 32 + hi4 * 8;
            bh[j] = *(const bf16x8*)(W2hi + off);
            bl[j] = *(const bf16x8*)(W2lo + off);
        }
        f32x4 a = {0.f, 0.f, 0.f, 0.f};
#pragma unroll
        for (int j = 0; j < 4; ++j) {
            a = MFMA16(ah[j], bh[j], a, 0, 0, 0);
            a = MFMA16(al[j], bh[j], a, 0, 0, 0);
            a = MFMA16(ah[j], bl[j], a, 0, 0, 0);
        }
#pragma unroll
        for (int q = 0; q < 4; ++q) {
            const int r = r0 + hi4 * 4 + q;
            if (r < n) G2[(size_t)r * FEAT + col] = f2bf(a[q] * dr[q]);
        }
    }
}

// ---------------- agg2 + fused CORAL head (r9) ----------------
__global__ __launch_bounds__(256) void agg_head(
    const u16* __restrict__ G, const int* __restrict__ rowp,
    const int* __restrict__ cnt, const int* __restrict__ bsum,
    const int* __restrict__ ssrc, const float* __restrict__ dis,
    const float* __restrict__ bias,
    float* __restrict__ out, const float* __restrict__ wfc,
    const float* __restrict__ thb, int n) {
    const int wave = threadIdx.x >> 6, lane = threadIdx.x & 63;
    const int nstride = (int)gridDim.x * 4;
    const u32* __restrict__ Gv = (const u32*)G;
    for (int node = blockIdx.x * 4 + wave; node < n; node += nstride) {
        const int c = cnt[node];
        const int beg = bsum[node >> 11] + rowp[node] - c;
        const int end = beg + c;
        u32 uself = Gv[(size_t)node * 64 + lane];
        float ax = blo(uself), ay = bhi(uself);
        int j = beg;
        for (; j + 16 <= end; j += 16) {
            int s[16];
#pragma unroll
            for (int u = 0; u < 16; ++u) s[u] = ssrc[j + u];
            u32 m[16];
#pragma unroll
            for (int u = 0; u < 16; ++u) m[u] = Gv[(size_t)s[u] * 64 + lane];
#pragma unroll
            for (int u = 0; u < 16; ++u) { ax += blo(m[u]); ay += bhi(m[u]); }
        }
        for (; j + 4 <= end; j += 4) {
            int s[4];
#pragma unroll
            for (int u = 0; u < 4; ++u) s[u] = ssrc[j + u];
            u32 m[4];
#pragma unroll
            for (int u = 0; u < 4; ++u) m[u] = Gv[(size_t)s[u] * 64 + lane];
#pragma unroll
            for (int u = 0; u < 4; ++u) { ax += blo(m[u]); ay += bhi(m[u]); }
        }
        for (; j < end; ++j) {
            u32 m = Gv[(size_t)ssrc[j] * 64 + lane];
            ax += blo(m); ay += bhi(m);
        }
        const float dn = dis[node];
        const float2 bv = ((const float2*)bias)[lane];
        const float o0 = fmaxf(fmaf(dn, ax, bv.x), 0.f);
        const float o1 = fmaxf(fmaf(dn, ay, bv.y), 0.f);
        const float2 wv = ((const float2*)wfc)[lane];
        float part = fmaf(o0, wv.x, o1 * wv.y);
#pragma unroll
        for (int m_ = 32; m_ >= 1; m_ >>= 1) part += __shfl_xor(part, m_, 64);
        if (lane < 4) out[(size_t)node * 4 + lane] = part + thb[lane];
    }
}

extern "C" void kernel_launch(void* const* d_in, const int* in_sizes, int n_in,
                              void* d_out, int out_size, void* d_ws, size_t ws_size,
                              hipStream_t stream) {
    const float* x   = (const float*)d_in[0];
    const int*   ei  = (const int*)d_in[1];
    const float* W1  = (const float*)d_in[2];
    const float* b1  = (const float*)d_in[3];
    const float* W2  = (const float*)d_in[4];
    const float* b2  = (const float*)d_in[5];
    const float* wfc = (const float*)d_in[6];
    const float* thb = (const float*)d_in[7];
    const int N = in_sizes[0] / FEAT;
    const int E = in_sizes[1] / 2;
    float* out = (float*)d_out;

    char* w = (char*)d_ws;
    int*   bsum  = (int*)w;                       // [<=256]
    int*   deg   = (int*)(w + 1024);              // [N]  (= cnt)
    int*   rowp  = deg + N;                       // [N]
    float* dis   = (float*)(rowp + N);            // [N]
    int*   src32 = (int*)(dis + N);               // [E]
    int*   dst32 = src32 + E;                     // [E]
    int*   ssrc  = dst32 + E;                     // [E]
    size_t off   = (((char*)(ssrc + E)) - w + 511) & ~(size_t)511;
    u16*   wh    = (u16*)(w + off);               // [2][128*128] hi (W1,W2)
    u16*   wl    = wh + 32768;                    // [2][128*128] lo
    u16*   g     = wl + 32768;                    // [N*128] bf16 plane (L1)
    u16*   g2    = g + (size_t)N * FEAT;          // [N*128] bf16 plane (L2)

    const int nper = (N + 7) / 8;
    const int nch  = (E + CHUNK - 1) / CHUNK;
    const int NB   = (N + 2047) / 2048;

    hipMemsetAsync(deg, 0, (size_t)N * 4, stream);
    compact_count<<<(E / 2 + 255) / 256, 256, 0, stream>>>(ei, src32, dst32, deg, E);
    scan1<<<NB, 256, 0, stream>>>(deg, rowp, bsum, dis, N);
    scan2<<<1, 256, 0, stream>>>(bsum, NB);
    fill_sorted<<<nch * 8, 256, 0, stream>>>(src32, dst32, rowp, bsum, ssrc, E, nper);

    conv_w<<<128, 256, 0, stream>>>(W1, W2, wh, wl);

    const int nt = (N + 15) / 16;
    gemm1<<<1024, 256, 0, stream>>>(x, wh, wl, dis, g, N, nt);
    agg_gemm<<<nt, 256, 0, stream>>>(g, rowp, deg, bsum, ssrc, dis, b1,
                                     wh + 16384, wl + 16384, g2, N);
    agg_head<<<4096, 256, 0, stream>>>(g2, rowp, deg, bsum, ssrc, dis, b2,
                                       out, wfc, thb, N);
}